// Round 1
// baseline (346.902 us; speedup 1.0000x reference)
//
#include <hip/hip_runtime.h>

#define TOKENS 32768
#define DIN 1024
#define DOUT 1024
#define RANK 16
#define SCALE1 0.5f
#define SCALE2 1.0f

#define BM 128
#define BN 128
#define BK 32

typedef __bf16 bf16x8 __attribute__((ext_vector_type(8)));
typedef float f32x4 __attribute__((ext_vector_type(4)));

// Async global->LDS, 16B per lane. LDS dest is wave-uniform base + lane*16.
__device__ __forceinline__ void load_lds16(const void* gptr, void* lptr) {
    __builtin_amdgcn_global_load_lds(
        (__attribute__((address_space(1))) void*)gptr,
        (__attribute__((address_space(3))) void*)lptr, 16, 0, 0);
}

// ---------------------------------------------------------------------------
// Kernel 1: Weff = W + 0.5*B1@A1 + 1.0*B2@A2, cast to bf16.  [DOUT, DIN]
// ---------------------------------------------------------------------------
__global__ void weff_kernel(const float* __restrict__ W, const float* __restrict__ A1,
                            const float* __restrict__ B1, const float* __restrict__ A2,
                            const float* __restrict__ B2, __bf16* __restrict__ Weff) {
    int idx = blockIdx.x * blockDim.x + threadIdx.x;  // over DOUT*DIN
    int o = idx >> 10;
    int i = idx & 1023;
    float s1 = 0.f, s2 = 0.f;
#pragma unroll
    for (int r = 0; r < RANK; ++r) {
        s1 += B1[o * RANK + r] * A1[r * DIN + i];
        s2 += B2[o * RANK + r] * A2[r * DIN + i];
    }
    Weff[idx] = (__bf16)(W[idx] + SCALE1 * s1 + SCALE2 * s2);
}

// ---------------------------------------------------------------------------
// Kernel 2: x fp32 -> bf16, 8 elems/thread, 16B stores.
// ---------------------------------------------------------------------------
__global__ void cvt_x_kernel(const float* __restrict__ x, __bf16* __restrict__ xb) {
    int i = (blockIdx.x * blockDim.x + threadIdx.x) * 8;
    float4 a = *(const float4*)(x + i);
    float4 b = *(const float4*)(x + i + 4);
    bf16x8 v;
    v[0] = (__bf16)a.x; v[1] = (__bf16)a.y; v[2] = (__bf16)a.z; v[3] = (__bf16)a.w;
    v[4] = (__bf16)b.x; v[5] = (__bf16)b.y; v[6] = (__bf16)b.z; v[7] = (__bf16)b.w;
    *(bf16x8*)(xb + i) = v;
}

// ---------------------------------------------------------------------------
// Kernel 3: out[M,N] = A[M,K] @ Bw[N,K]^T + bias.  m97-style 128x128 tile.
// ---------------------------------------------------------------------------
__global__ __launch_bounds__(256) void gemm_bt_kernel(
    const __bf16* __restrict__ A,   // [TOKENS, DIN] bf16
    const __bf16* __restrict__ Bw,  // [DOUT, DIN] bf16
    const float* __restrict__ bias, float* __restrict__ C) {
    __shared__ __bf16 lsA[BM * BK];  // 8 KB, row-major stride BK (unpadded: load_lds layout)
    __shared__ __bf16 lsB[BN * BK];  // 8 KB

    const int tid = threadIdx.x;
    const int wave = tid >> 6;
    const int lane = tid & 63;
    const int m0 = blockIdx.y * BM;
    const int n0 = blockIdx.x * BN;
    const int wm = wave >> 1;  // 0..1
    const int wn = wave & 1;   // 0..1

    // Staging: each wave covers 32 rows of each tile via 2 load_lds16 insts.
    // lane l -> relative row l>>2, byte col (l&3)*16; byte offset == l*16.
    const int lrow = lane >> 2;
    const int lcol = (lane & 3) * 8;  // element offset within 32-wide K-tile

    const __bf16* gA = A + (size_t)(m0 + wave * 32 + lrow) * DIN + lcol;
    const __bf16* gB = Bw + (size_t)(n0 + wave * 32 + lrow) * DIN + lcol;
    __bf16* lA0 = &lsA[(wave * 32) * BK];
    __bf16* lA1 = &lsA[(wave * 32 + 16) * BK];
    __bf16* lB0 = &lsB[(wave * 32) * BK];
    __bf16* lB1 = &lsB[(wave * 32 + 16) * BK];

    f32x4 acc[4][4];
#pragma unroll
    for (int i = 0; i < 4; ++i)
#pragma unroll
        for (int j = 0; j < 4; ++j) acc[i][j] = f32x4{0.f, 0.f, 0.f, 0.f};

    // Fragment addressing: A[m=lane&15][k=(lane>>4)*8+j]; same pattern for B.
    const int fr = lane & 15;
    const int fq = (lane >> 4) * 8;

    for (int k0 = 0; k0 < DIN; k0 += BK) {
        load_lds16(gA + k0, lA0);
        load_lds16(gA + k0 + 16 * DIN, lA1);
        load_lds16(gB + k0, lB0);
        load_lds16(gB + k0 + 16 * DIN, lB1);
        __syncthreads();  // compiler emits vmcnt(0) drain before barrier

        bf16x8 af[4], bfv[4];
#pragma unroll
        for (int t = 0; t < 4; ++t) {
            af[t] = *(const bf16x8*)&lsA[(wm * 64 + t * 16 + fr) * BK + fq];
            bfv[t] = *(const bf16x8*)&lsB[(wn * 64 + t * 16 + fr) * BK + fq];
        }
#pragma unroll
        for (int mt = 0; mt < 4; ++mt)
#pragma unroll
            for (int nt = 0; nt < 4; ++nt)
                acc[mt][nt] = __builtin_amdgcn_mfma_f32_16x16x32_bf16(
                    af[mt], bfv[nt], acc[mt][nt], 0, 0, 0);
        __syncthreads();
    }

    // Epilogue: C/D layout col = lane&15, row = (lane>>4)*4 + reg.
    const int rbase = (lane >> 4) * 4;
#pragma unroll
    for (int nt = 0; nt < 4; ++nt) {
        const int n = n0 + wn * 64 + nt * 16 + fr;
        const float bv = bias[n];
#pragma unroll
        for (int mt = 0; mt < 4; ++mt) {
            const int m = m0 + wm * 64 + mt * 16 + rbase;
            float* cp = C + (size_t)m * DOUT + n;
#pragma unroll
            for (int r = 0; r < 4; ++r) cp[(size_t)r * DOUT] = acc[mt][nt][r] + bv;
        }
    }
}

// ---------------------------------------------------------------------------
extern "C" void kernel_launch(void* const* d_in, const int* in_sizes, int n_in,
                              void* d_out, int out_size, void* d_ws, size_t ws_size,
                              hipStream_t stream) {
    const float* x  = (const float*)d_in[0];
    const float* W  = (const float*)d_in[1];
    const float* b  = (const float*)d_in[2];
    const float* A1 = (const float*)d_in[3];
    const float* B1 = (const float*)d_in[4];
    const float* A2 = (const float*)d_in[5];
    const float* B2 = (const float*)d_in[6];
    float* out = (float*)d_out;

    // Workspace: [x_bf16: 64 MB][Weff_bf16: 2 MB]
    __bf16* xb   = (__bf16*)d_ws;
    __bf16* Weff = (__bf16*)((char*)d_ws + (size_t)TOKENS * DIN * sizeof(__bf16));

    cvt_x_kernel<<<TOKENS * DIN / (256 * 8), 256, 0, stream>>>(x, xb);
    weff_kernel<<<DOUT * DIN / 256, 256, 0, stream>>>(W, A1, B1, A2, B2, Weff);
    // Grid: n-tiles fastest so the 8 n-blocks sharing an A-tile are adjacent in
    // dispatch order (A-tile L2 reuse); Weff (2 MB) stays resident in per-XCD L2.
    gemm_bt_kernel<<<dim3(DOUT / BN, TOKENS / BM), 256, 0, stream>>>(xb, Weff, b, out);
}